// Round 7
// baseline (347.851 us; speedup 1.0000x reference)
//
#include <hip/hip_runtime.h>

#define NN 500000
#define FF 128
#define HH 128
#define BB 32768
#define KHOPS 4
#define EPER 524288              // RWS * B = 2^19
#define KE (KHOPS * EPER)        // 2097152
#define NOUT 8
#define SBLK 256                 // sort blocks
#define EPB (KE / SBLK)          // 8192 edges per sort block
#define GEMM_TILES 3907          // ceil(NN/128)

typedef unsigned short u16;
typedef unsigned char u8;
typedef __attribute__((ext_vector_type(8))) short short8v;   // 8 bf16 (4 VGPRs)
typedef __attribute__((ext_vector_type(4))) float f32x4;
typedef __attribute__((ext_vector_type(2))) float f32x2;

__device__ __forceinline__ float bflo(unsigned int u) {
    union { unsigned int x; float f; } t; t.x = u << 16; return t.f;
}
__device__ __forceinline__ float bfhi(unsigned int u) {
    union { unsigned int x; float f; } t; t.x = u & 0xFFFF0000u; return t.f;
}
__device__ __forceinline__ u16 f2bf(float f) {
    union { float f; unsigned int u; } t; t.f = f;
    unsigned int u = t.u;
    unsigned int r = (u + 0x7FFFu + ((u >> 16) & 1u)) >> 16;   // RNE
    return (u16)r;
}

// ---------- pre1: hist2(0..255) | degsum(256) | packW0(257) | dis(258..) ----------
__launch_bounds__(256, 2)
__global__ void k_pre1(const int* __restrict__ heads, u8* __restrict__ M,
                       const float* __restrict__ deg, const int* __restrict__ batch,
                       float* __restrict__ dsum, const float* __restrict__ W0,
                       u16* __restrict__ w0p, float* __restrict__ dis) {
    __shared__ unsigned int hp[8192];    // 32 KB (hist) / reused as reduce buf
    int tid = threadIdx.x;
    int bid = blockIdx.x;
    if (bid < SBLK) {
        // per-block histogram of heads into M[bid][BB] (u8, 4-packed)
        #pragma unroll
        for (int j = 0; j < 32; j++) hp[tid + j * 256] = 0;
        __syncthreads();
        int ebase = bid * EPB;
        #pragma unroll 4
        for (int it = 0; it < EPB / 256; it++) {
            int b = heads[ebase + it * 256 + tid];
            atomicAdd(&hp[b >> 2], 1u << ((b & 3) * 8));
        }
        __syncthreads();
        unsigned int* M32 = (unsigned int*)(M + (size_t)bid * BB);
        #pragma unroll
        for (int j = 0; j < 32; j++) {
            int w = tid + j * 256;
            M32[w] = hp[w];
        }
    } else if (bid == SBLK) {
        // deg-sum over batch (single block, 4 independent partials per thread)
        float* red = (float*)hp;
        float a0 = 0.f, a1 = 0.f, a2 = 0.f, a3 = 0.f;
        for (int i = tid; i < BB; i += 1024) {
            a0 += deg[batch[i]];
            a1 += deg[batch[i + 256]];
            a2 += deg[batch[i + 512]];
            a3 += deg[batch[i + 768]];
        }
        red[tid] = (a0 + a1) + (a2 + a3);
        __syncthreads();
        for (int off = 128; off > 0; off >>= 1) {
            if (tid < off) red[tid] += red[tid + off];
            __syncthreads();
        }
        if (tid == 0) dsum[0] = red[0];
    } else if (bid == SBLK + 1) {
        // pack W0 into MFMA B-fragment order, bf16
        for (int r = 0; r < 64; r++) {
            int f = r * 256 + tid;
            int k = f >> 7, c = f & 127;
            int kt = k >> 5, i = k & 7, lh = (k >> 3) & 3;
            int lane = lh * 16 + (c & 15), n = c >> 4;
            w0p[(((kt * 8 + n) * 64 + lane) << 3) + i] = f2bf(W0[f]);
        }
    } else {
        // dis[i] = rsqrt(deg[i])
        int i0 = (bid - SBLK - 2) * 1024 + tid * 4;
        if (i0 < NN) {                       // NN % 4 == 0
            float4 d = *(const float4*)&deg[i0];
            float4 o;
            o.x = rsqrtf(d.x); o.y = rsqrtf(d.y);
            o.z = rsqrtf(d.z); o.w = rsqrtf(d.w);
            *(float4*)&dis[i0] = o;
        }
    }
}

// ---------- pre2: colscan u32-packed (0..31) | disb (32..63) ----------
__global__ void k_pre2(u8* __restrict__ M, int* __restrict__ colsum,
                       const float* __restrict__ deg, const int* __restrict__ batch,
                       const float* __restrict__ dsum, float* __restrict__ disb) {
    int tid = threadIdx.x;
    if (blockIdx.x < 32) {
        // exclusive prefix down each key column, 4 keys/thread byte-parallel
        int g = blockIdx.x * 256 + tid;          // key-group (8192 total)
        unsigned int* M32 = (unsigned int*)M;
        unsigned int run = 0;
        #pragma unroll 8
        for (int b = 0; b < SBLK; b++) {
            size_t idx = (size_t)b * (BB / 4) + g;
            unsigned int v = M32[idx];
            M32[idx] = run;
            run += v;     // per-byte totals <= ~120, no cross-byte carry
        }
        colsum[g * 4 + 0] = (int)(run & 0xFFu);
        colsum[g * 4 + 1] = (int)((run >> 8) & 0xFFu);
        colsum[g * 4 + 2] = (int)((run >> 16) & 0xFFu);
        colsum[g * 4 + 3] = (int)((run >> 24) & 0xFFu);
    } else {
        // disb[b] = rsqrt(deg[batch[b]]) * dsum/EPER
        int b0 = (blockIdx.x - 32) * 1024 + tid * 4;
        float sc = dsum[0] * (1.0f / (float)EPER);
        #pragma unroll
        for (int t = 0; t < 4; t++) {
            int b = b0 + t;
            disb[b] = rsqrtf(deg[batch[b]]) * sc;
        }
    }
}

// ---------- scan of colsum -> base (single block, 1024 thr x 32) ----------
__global__ void k_scan(const int* __restrict__ colsum, int* __restrict__ base) {
    __shared__ int sc[1024];
    int tid = threadIdx.x;
    int loc[32];
    int run = 0;
    #pragma unroll
    for (int j = 0; j < 32; j++) {
        loc[j] = run;
        run += colsum[tid * 32 + j];
    }
    sc[tid] = run;
    __syncthreads();
    for (int off = 1; off < 1024; off <<= 1) {
        int v = (tid >= off) ? sc[tid - off] : 0;
        __syncthreads();
        sc[tid] += v;
        __syncthreads();
    }
    int excl = sc[tid] - run;
    #pragma unroll
    for (int j = 0; j < 32; j++) base[tid * 32 + j] = excl + loc[j];
    if (tid == 1023) base[BB] = sc[1023];     // = KE
}

// ---------- fused: scatter2 (blocks 0..255) + GEMM1 MFMA (blocks 256..) ----------
// scatter2 rides free under the HBM-bound GEMM. Weight fully precomputed here
// so the gather inner loop is load+FMA only.
__launch_bounds__(256, 2)
__global__ void k_fused(const float* __restrict__ x, const u16* __restrict__ w0p,
                        const float* __restrict__ b0, u16* __restrict__ h,
                        const int* __restrict__ heads, const int* __restrict__ ends,
                        const u8* __restrict__ M, const int* __restrict__ base,
                        const float* __restrict__ dis, const float* __restrict__ disb,
                        const float* __restrict__ att, uint2* __restrict__ ewp) {
    __shared__ char smem[65536];
    int tid = threadIdx.x;

    if (blockIdx.x < SBLK) {
        // ---- scatter (e, w) into pos = base[b] + M[blk][b] + local rank ----
        unsigned int* hp = (unsigned int*)smem;
        int blk = blockIdx.x;
        float attk = att[(blk >> 6) + 1];      // 64 sort blocks per hop
        #pragma unroll
        for (int j = 0; j < 32; j++) hp[tid + j * 256] = 0;
        __syncthreads();
        int ebase = blk * EPB;
        for (int it = 0; it < EPB / 256; it++) {
            int i = ebase + it * 256 + tid;
            int b = heads[i];
            int e = ends[i];
            float w = attk * disb[b] * dis[e];
            unsigned int old = atomicAdd(&hp[b >> 2], 1u << ((b & 3) * 8));
            unsigned int rank = (old >> ((b & 3) * 8)) & 0xFFu;
            int pos = base[b] + (int)M[(size_t)blk * BB + b] + (int)rank;
            uint2 pw;
            pw.x = (unsigned int)e;
            pw.y = __float_as_uint(w);
            ewp[pos] = pw;
        }
        return;
    }

    // ---- GEMM1: h = bf16(relu(x @ W0 + b0)) for a 128-row tile ----
    u16* xs = (u16*)smem;                 // 32 KB, XOR-swizzled bf16 A-tile
    u16* ws = (u16*)(smem + 32768);       // 32 KB, packed B fragments
    int wid = tid >> 6;
    int lane = tid & 63;
    long rowbase = (long)(blockIdx.x - SBLK) * 128;

    #pragma unroll
    for (int r = 0; r < 8; r++) {
        int f = tid + r * 256;            // 2048 x 16B
        *(float4*)&ws[f * 8] = *(const float4*)&w0p[f * 8];
    }
    #pragma unroll
    for (int r = 0; r < 16; r++) {
        int f = tid + r * 256;            // 4096 float4
        int row = f >> 5;
        int c4 = (f & 31) * 4;
        long grow = rowbase + row; if (grow >= NN) grow = NN - 1;   // clamp tail
        float4 v = *(const float4*)&x[grow * 128 + c4];
        ushort4 pv;
        pv.x = f2bf(v.x); pv.y = f2bf(v.y); pv.z = f2bf(v.z); pv.w = f2bf(v.w);
        int byte = row * 256 + ((c4 * 2) ^ ((row & 7) << 4));
        *(ushort4*)((char*)xs + byte) = pv;
    }
    __syncthreads();

    short8v a[2][4];
    #pragma unroll
    for (int rs = 0; rs < 2; rs++) {
        int row = wid * 32 + rs * 16 + (lane & 15);
        int sw = (row & 7) << 4;
        #pragma unroll
        for (int kt = 0; kt < 4; kt++) {
            int kb = kt * 64 + (lane >> 4) * 16;
            a[rs][kt] = *(const short8v*)((const char*)xs + row * 256 + (kb ^ sw));
        }
    }

    f32x4 acc[2][8] = {};
    #pragma unroll
    for (int n = 0; n < 8; n++) {
        short8v bfr[4];
        #pragma unroll
        for (int kt = 0; kt < 4; kt++)
            bfr[kt] = *(const short8v*)&ws[(((kt * 8 + n) * 64 + lane) << 3)];
        #pragma unroll
        for (int rs = 0; rs < 2; rs++) {
            #pragma unroll
            for (int kt = 0; kt < 4; kt++)
                acc[rs][n] = __builtin_amdgcn_mfma_f32_16x16x32_bf16(
                                 a[rs][kt], bfr[kt], acc[rs][n], 0, 0, 0);
        }
    }

    float b0v[8];
    #pragma unroll
    for (int n = 0; n < 8; n++) b0v[n] = b0[n * 16 + (lane & 15)];

    // stage relu(acc)+b0 into wave-private 8 KB stripe, then coalesced dwordx4
    u16* xw = &xs[wid * 32 * 128];
    #pragma unroll
    for (int rs = 0; rs < 2; rs++) {
        #pragma unroll
        for (int r = 0; r < 4; r++) {
            int row = rs * 16 + (lane >> 4) * 4 + r;      // 0..31 in stripe
            int sw = (row & 7) << 4;
            #pragma unroll
            for (int n = 0; n < 8; n++) {
                float v = acc[rs][n][r] + b0v[n];
                v = v > 0.f ? v : 0.f;
                int byte = row * 256 + ((n * 32 + (lane & 15) * 2) ^ sw);
                *(u16*)((char*)xw + byte) = f2bf(v);
            }
        }
    }
    __syncthreads();
    #pragma unroll
    for (int pass = 0; pass < 8; pass++) {
        int off = pass * 1024 + lane * 16;   // byte offset in stripe
        int row = off >> 8;                  // 0..31
        int colb = off & 255;
        int ocolb = colb ^ ((row & 7) << 4);
        long grow = rowbase + wid * 32 + row;
        uint4 v = *(const uint4*)((const char*)xw + off);
        if (grow < NN)
            *(uint4*)((char*)&h[grow * 128] + ocolb) = v;
    }
}

// ---------- gather: P[b,:] = att0*h[batch[b],:] + sum_j w_j * h[end_j,:] ----------
// 4 waves/block, wave owns row b. Quarter-wave q owns edge j+u*4+q; lane owns
// 8 cols. Inner loop is pure {b64 broadcast, dwordx4 row, pk-FMA} — weights
// precomputed in scatter.
__launch_bounds__(256)
__global__ void k_gather(const u16* __restrict__ h, const int* __restrict__ batch,
                         const int* __restrict__ base, const uint2* __restrict__ ewp,
                         const float* __restrict__ att,
                         float* __restrict__ P, float* __restrict__ s) {
    int b = blockIdx.x * 4 + (threadIdx.x >> 6);
    int l = threadIdx.x & 63;
    int q = l >> 4;
    int c8 = (l & 15) * 8;            // owns cols c8..c8+7
    float att0 = att[0];
    f32x2 acc2[4] = {{0.f, 0.f}, {0.f, 0.f}, {0.f, 0.f}, {0.f, 0.f}};
    float wsum = 0.f;

    if (q == 0) {
        int nb = batch[b];
        uint4 v = *(const uint4*)&h[(size_t)nb * 128 + c8];
        acc2[0] = f32x2{att0 * bflo(v.x), att0 * bfhi(v.x)};
        acc2[1] = f32x2{att0 * bflo(v.y), att0 * bfhi(v.y)};
        acc2[2] = f32x2{att0 * bflo(v.z), att0 * bfhi(v.z)};
        acc2[3] = f32x2{att0 * bflo(v.w), att0 * bfhi(v.w)};
    }

    int beg = base[b], fin = base[b + 1];
    for (int j = beg; j < fin; j += 32) {
        uint2 pw[8];
        #pragma unroll
        for (int u = 0; u < 8; u++) {
            int je = j + u * 4 + q;
            int jc = je < fin ? je : beg;     // always-valid index
            pw[u] = ewp[jc];
            if (je >= fin) pw[u].y = 0u;      // w = +0.0f
        }
        uint4 v[8];
        #pragma unroll
        for (int u = 0; u < 8; u++)
            v[u] = *(const uint4*)&h[(size_t)pw[u].x * 128 + c8];
        #pragma unroll
        for (int u = 0; u < 8; u++) {
            float w = __uint_as_float(pw[u].y);
            f32x2 w2 = {w, w};
            acc2[0] = __builtin_elementwise_fma(w2, f32x2{bflo(v[u].x), bfhi(v[u].x)}, acc2[0]);
            acc2[1] = __builtin_elementwise_fma(w2, f32x2{bflo(v[u].y), bfhi(v[u].y)}, acc2[1]);
            acc2[2] = __builtin_elementwise_fma(w2, f32x2{bflo(v[u].z), bfhi(v[u].z)}, acc2[2]);
            acc2[3] = __builtin_elementwise_fma(w2, f32x2{bflo(v[u].w), bfhi(v[u].w)}, acc2[3]);
            wsum += w;
        }
    }
    float accf[8] = { acc2[0].x, acc2[0].y, acc2[1].x, acc2[1].y,
                      acc2[2].x, acc2[2].y, acc2[3].x, acc2[3].y };
    #pragma unroll
    for (int k = 0; k < 8; k++) {
        accf[k] += __shfl_xor(accf[k], 16);
        accf[k] += __shfl_xor(accf[k], 32);
    }
    wsum += __shfl_xor(wsum, 16);
    wsum += __shfl_xor(wsum, 32);

    if (q == 0) {
        float4 o0 = { accf[0], accf[1], accf[2], accf[3] };
        float4 o1 = { accf[4], accf[5], accf[6], accf[7] };
        *(float4*)&P[(size_t)b * 128 + c8]     = o0;
        *(float4*)&P[(size_t)b * 128 + c8 + 4] = o1;
        if (l == 0) s[b] = att0 + wsum;
    }
}

// ---------- fused epilogue: aggx = P@W1 + s*b1; relu; @W2 + b2; log_softmax ----------
__launch_bounds__(256, 2)
__global__ void k_out(const float* __restrict__ P, const float* __restrict__ s,
                      const float* __restrict__ W1, const float* __restrict__ b1,
                      const float* __restrict__ W2, const float* __restrict__ b2,
                      float* __restrict__ out) {
    __shared__ float W1s[128 * 128];  // 64 KB
    __shared__ float Ps[32 * 128];    // 16 KB, reused as relu(aggx)
    int tid = threadIdx.x;
    int rowbase = blockIdx.x * 32;
    #pragma unroll
    for (int rep = 0; rep < 16; rep++) {
        int f = tid + rep * 256;
        *(float4*)&W1s[f * 4] = *(const float4*)&W1[f * 4];
    }
    #pragma unroll
    for (int rep = 0; rep < 4; rep++) {
        int f = tid + rep * 256;
        *(float4*)&Ps[f * 4] = *(const float4*)&P[(size_t)rowbase * 128 + f * 4];
    }
    __syncthreads();

    int c0 = (tid & 31) * 4;
    int r0 = (tid >> 5) * 4;
    float b1r[4] = { b1[c0], b1[c0 + 1], b1[c0 + 2], b1[c0 + 3] };
    float sv[4];
    #pragma unroll
    for (int j = 0; j < 4; j++) sv[j] = s[rowbase + r0 + j];

    float acc[4][4] = {};
    #pragma unroll 2
    for (int i = 0; i < 128; i += 4) {
        float4 xq[4], wq4[4];
        #pragma unroll
        for (int j = 0; j < 4; j++) xq[j]  = *(const float4*)&Ps[(r0 + j) * 128 + i];
        #pragma unroll
        for (int q = 0; q < 4; q++) wq4[q] = *(const float4*)&W1s[(i + q) * 128 + c0];
        #pragma unroll
        for (int j = 0; j < 4; j++) {
            float xv[4] = { xq[j].x, xq[j].y, xq[j].z, xq[j].w };
            #pragma unroll
            for (int q = 0; q < 4; q++) {
                acc[j][0] += xv[q] * wq4[q].x;
                acc[j][1] += xv[q] * wq4[q].y;
                acc[j][2] += xv[q] * wq4[q].z;
                acc[j][3] += xv[q] * wq4[q].w;
            }
        }
    }
    __syncthreads();                  // all reads of Ps done before overwrite
    #pragma unroll
    for (int j = 0; j < 4; j++) {
        #pragma unroll
        for (int c = 0; c < 4; c++) {
            float v = acc[j][c] + sv[j] * b1r[c];
            Ps[(r0 + j) * 128 + c0 + c] = v > 0.f ? v : 0.f;
        }
    }
    __syncthreads();

    int row = tid >> 3;
    int o = tid & 7;
    int rot = (row * 4) & 127;
    float v = b2[o];
    #pragma unroll 4
    for (int ii = 0; ii < 128; ii++) {
        int i = (ii + rot) & 127;
        v += Ps[row * 128 + i] * W2[i * 8 + o];
    }
    float m = v;
    for (int d = 1; d < 8; d <<= 1) m = fmaxf(m, __shfl_xor(m, d, 8));
    float ex = expf(v - m);
    float sum = ex;
    for (int d = 1; d < 8; d <<= 1) sum += __shfl_xor(sum, d, 8);
    out[(size_t)(rowbase + row) * 8 + o] = (v - m) - logf(sum);
}

extern "C" void kernel_launch(void* const* d_in, const int* in_sizes, int n_in,
                              void* d_out, int out_size, void* d_ws, size_t ws_size,
                              hipStream_t stream) {
    const float* x     = (const float*)d_in[0];
    const float* W0    = (const float*)d_in[1];
    const float* b0    = (const float*)d_in[2];
    const float* W1    = (const float*)d_in[3];
    const float* b1    = (const float*)d_in[4];
    const float* W2    = (const float*)d_in[5];
    const float* b2    = (const float*)d_in[6];
    const float* att   = (const float*)d_in[7];
    const float* deg   = (const float*)d_in[8];
    const int*   batch = (const int*)d_in[9];
    const int*   heads = (const int*)d_in[10];
    const int*   ends  = (const int*)d_in[11];
    float* out = (float*)d_out;

    char* w = (char*)d_ws;
    size_t off = 0;
    u16* h = (u16*)(w + off);          off += (size_t)NN * 128 * 2;       // 128 MB
    float* P = (float*)(w + off);      off += (size_t)BB * 128 * 4;       // 16 MB
    float* s = (float*)(w + off);      off += (size_t)BB * 4;
    int* base = (int*)(w + off);       off += 131328;                     // (B+1)*4 padded
    uint2* ewp = (uint2*)(w + off);    off += (size_t)KE * 8;             // (e, w)
    u8* M = (u8*)(w + off);            off += (size_t)SBLK * BB;          // 8 MB hist
    int* colsum = (int*)(w + off);     off += (size_t)BB * 4;
    float* dis = (float*)(w + off);    off += (size_t)NN * 4;             // rsqrt(deg)
    float* disb = (float*)(w + off);   off += (size_t)BB * 4;
    float* dsum = (float*)(w + off);   off += 256;
    u16* w0p = (u16*)(w + off);        off += 16384 * 2;                  // packed W0

    int disBlocks = (NN + 1023) / 1024;                 // 489
    k_pre1<<<SBLK + 2 + disBlocks, 256, 0, stream>>>(heads, M, deg, batch,
                                                     dsum, W0, w0p, dis);
    k_pre2<<<64, 256, 0, stream>>>(M, colsum, deg, batch, dsum, disb);
    k_scan<<<1, 1024, 0, stream>>>(colsum, base);
    k_fused<<<SBLK + GEMM_TILES, 256, 0, stream>>>(x, w0p, b0, h, heads, ends,
                                                   M, base, dis, disb, att, ewp);
    k_gather<<<BB / 4, 256, 0, stream>>>(h, batch, base, ewp, att, P, s);
    k_out<<<BB / 32, 256, 0, stream>>>(P, s, W1, b1, W2, b2, out);
}